// Round 8
// baseline (178.800 us; speedup 1.0000x reference)
//
#include <hip/hip_runtime.h>
#include <hip/hip_bf16.h>
#include <math.h>

// DIN forward, MI355X gfx950. B=32,N=256,L=50, D=48; feat 128 -> 200 -> 80 -> 1.
// Algebra: ai@W1 = qc + [he | he*q] @ Wcat   (Wcat constant across bn)
//   qc = q@(W1a+W1c) + b1 via MFMA with folded bias row (k=48 -> 1*b1)
//   LAU layers 2+3 collapse: score = relu(h1) . (W2@w3) + (b2@w3+b3)
// k0_prep: all weights as bf16 MFMA B-fragments in ws.
// kA_attn: per-bn attention, fully wave-private, ZERO barriers, register-indexed
//          gathers, 25.9 KB LDS -> 6 blocks/CU. Writes feat[8192][128] bf16.
// k2_fc:   128->200->80->1 MLP via MFMA, 1 wave = 16 rows (round-4 proven).
// k3:      masked softmax over N=256.

typedef short short8 __attribute__((ext_vector_type(8)));
typedef float f32x4 __attribute__((ext_vector_type(4)));

#define NL 50
#define BN_TOT 8192

__device__ __forceinline__ ushort f2bf(float x) {
    union { __hip_bfloat16 b; ushort u; } c;
    c.b = __float2bfloat16(x);          // RNE
    return c.u;
}
__device__ __forceinline__ float bf2f(ushort h) {
    union { uint u; float f; } v; v.u = ((uint)h) << 16;
    return v.f;
}
__device__ __forceinline__ void wave_lds_fence() {
    asm volatile("s_waitcnt lgkmcnt(0)" ::: "memory");
}

// ---- ws layout (bytes) ----
#define WS_FEAT   0                       // bf16 8192*128  = 2097152
#define WS_LOGITS 2097152                 // f32  8192
#define WS_W1FRAG 2129920                 // bf16 52*512
#define WS_W2FRAG 2183168                 // bf16 42*512
#define WS_WCFRAG 2226176                 // bf16 12*512
#define WS_WACF   2238464                 // bf16 8*512
#define WS_W23    2250752                 // f32  64
#define WS_C23    2251008                 // f32  1

// ================= k0_prep: weight fragments =================
__global__ __launch_bounds__(256) void k0_prep(
    const float* __restrict__ aw1, const float* __restrict__ ab1,
    const float* __restrict__ ab2,
    const float* __restrict__ aw2, const float* __restrict__ aw3,
    const float* __restrict__ ab3,
    const float* __restrict__ fw1, const float* __restrict__ fw2,
    ushort* __restrict__ W1frag, ushort* __restrict__ W2frag,
    ushort* __restrict__ WcFrag, ushort* __restrict__ WacF,
    float* __restrict__ w23, float* __restrict__ c23)
{
    const int b = blockIdx.x, t = threadIdx.x;
    if (b < 104) {                       // W1frag: fw1[128][200] -> 13nt x 4ks
        int e = b * 256 + t;
        if (e < 26624) {
            int f = e >> 9, r = e & 511, l = r >> 3, j = r & 7;
            int nt = f >> 2, ks = f & 3;
            int k = ks * 32 + (l >> 4) * 8 + j, n = nt * 16 + (l & 15);
            float v = (n < 200) ? fw1[k * 200 + n] : 0.f;
            W1frag[e] = f2bf(v);
        }
    } else if (b < 188) {                // W2frag: fw2[200][80] -> 6nt x 7ks (pad K224,N96)
        int e = (b - 104) * 256 + t;
        if (e < 21504) {
            int f = e >> 9, r = e & 511, l = r >> 3, j = r & 7;
            int nt = f / 7, ks = f % 7;
            int k = ks * 32 + (l >> 4) * 8 + j, n = nt * 16 + (l & 15);
            float v = (k < 200 && n < 80) ? fw2[k * 80 + n] : 0.f;
            W2frag[e] = f2bf(v);
        }
    } else if (b < 212) {                // WcFrag: Wcat[96][64] -> 4nt x 3ks
        int e = (b - 188) * 256 + t;     // 6144 elems
        int f = e >> 9, r = e & 511, l = r >> 3, j = r & 7;
        int nt = f / 3, ks = f % 3;
        int k = ks * 32 + (l >> 4) * 8 + j, n = nt * 16 + (l & 15);
        float v = (k < 48) ? (aw1[(48 + k) * 64 + n] - aw1[(96 + k) * 64 + n])
                           : aw1[(144 + (k - 48)) * 64 + n];
        WcFrag[e] = f2bf(v);
    } else if (b < 228) {                // WacF: (W1a+W1c)[48][64] + bias row k=48
        int e = (b - 212) * 256 + t;     // 4096 elems
        int f = e >> 9, r = e & 511, l = r >> 3, j = r & 7;
        int nt = f >> 1, ks = f & 1;
        int k = ks * 32 + (l >> 4) * 8 + j, n = nt * 16 + (l & 15);
        float v = (k < 48) ? (aw1[k * 64 + n] + aw1[(96 + k) * 64 + n])
                           : ((k == 48) ? ab1[n] : 0.f);
        WacF[e] = f2bf(v);
    } else {                             // w23, c23
        if (t < 64) {
            float s = 0.f;
            #pragma unroll
            for (int jj = 0; jj < 16; ++jj) s = fmaf(aw2[t * 16 + jj], aw3[jj], s);
            w23[t] = s;
        }
        if (t == 64) {
            float c = ab3[0];
            #pragma unroll
            for (int jj = 0; jj < 16; ++jj) c = fmaf(ab2[jj], aw3[jj], c);
            c23[0] = c;
        }
    }
}

// ================= kA: attention (1 wave = 1 bn, no barriers) =================
__device__ __forceinline__ short8 lds8(const ushort* hb, int row, int c) {
    return *(const short8*)&hb[row * 56 + c * 8];
}
__device__ __forceinline__ short8 scale8(const ushort* hb, const float* qv,
                                         int row, int c, int qb) {
    short8 a = lds8(hb, row, c);
    union { short8 v; ushort s[8]; } o;
    const ushort* as = (const ushort*)&a;
    #pragma unroll
    for (int j = 0; j < 8; ++j) o.s[j] = f2bf(bf2f(as[j]) * qv[qb + j]);
    return o.v;
}
__device__ __forceinline__ short8 cvt8(float4 f0, float4 f1) {
    union { short8 v; ushort s[8]; } o;
    o.s[0] = f2bf(f0.x); o.s[1] = f2bf(f0.y); o.s[2] = f2bf(f0.z); o.s[3] = f2bf(f0.w);
    o.s[4] = f2bf(f1.x); o.s[5] = f2bf(f1.y); o.s[6] = f2bf(f1.z); o.s[7] = f2bf(f1.w);
    return o.v;
}

__global__ __launch_bounds__(256, 6) void kA_attn(
    const float* __restrict__ emb_user,
    const float* __restrict__ emb_item,
    const float* __restrict__ emb_cate,
    const int* __restrict__ user,
    const int* __restrict__ items,
    const int* __restrict__ cates,
    const int* __restrict__ ii,
    const int* __restrict__ ic,
    const ushort* __restrict__ WcFrag,
    const ushort* __restrict__ WacF,
    const float* __restrict__ w23g,
    const float* __restrict__ c23g,
    ushort* __restrict__ feat)
{
    __shared__ __align__(16) char LDSBUF[25856];
    ushort* hebA  = (ushort*)LDSBUF;                 // [4][50*56] bf16   (22400 B)
    float*  qfA   = (float*) (LDSBUF + 22400);       // [4][48]
    float*  qclA  = (float*) (LDSBUF + 23168);       // [4][64]
    float*  sclA  = (float*) (LDSBUF + 24192);       // [4][52]
    int*    imlA  = (int*)   (LDSBUF + 25024);       // [4][52]

    const int t = threadIdx.x;
    const int w = t >> 6, l = t & 63;
    const int bn = blockIdx.x * 4 + w;
    const int col = l & 15, g = l >> 4;

    ushort* hb = hebA + w * 2800;
    float*  qv = qfA + w * 48;

    const int it_ = items[bn], ct = cates[bn], ur = user[bn];
    const size_t fb = (size_t)bn * 128;

    // ---- P0: q (LDS + feat), u (feat direct), iml ----
    if (l < 6) {
        const float* p = (l < 4) ? emb_item + (size_t)it_ * 32 + l * 8
                                 : emb_cate + (size_t)ct * 16 + (l - 4) * 8;
        float4 f0 = *(const float4*)p, f1 = *(const float4*)(p + 4);
        *(float4*)&qv[l * 8]     = f0;
        *(float4*)&qv[l * 8 + 4] = f1;
        *(short8*)&feat[fb + l * 8] = cvt8(f0, f1);
    } else if (l >= 8 && l < 12) {
        const float* p = emb_user + (size_t)ur * 32 + (l - 8) * 8;
        float4 f0 = *(const float4*)p, f1 = *(const float4*)(p + 4);
        *(short8*)&feat[fb + 96 + (l - 8) * 8] = cvt8(f0, f1);
    }
    if (l < NL) imlA[w * 52 + l] = ii[(size_t)bn * NL + l];

    // ---- P1: he gather, register-resident indices (no LDS bounce) ----
    {
        int idxs[5];
        #pragma unroll
        for (int j = 0; j < 5; ++j) {
            int e = 64 * j + l;
            if (e < 300) {
                int row = e / 6, c = e - row * 6;
                idxs[j] = (c < 4) ? ii[(size_t)bn * NL + row]
                                  : ic[(size_t)bn * NL + row];
            }
        }
        #pragma unroll
        for (int j = 0; j < 5; ++j) {
            int e = 64 * j + l;
            if (e < 300) {
                int row = e / 6, c = e - row * 6;
                int k0 = c * 8;
                const float* src = (k0 < 32)
                    ? emb_item + (size_t)idxs[j] * 32 + k0
                    : emb_cate + (size_t)idxs[j] * 16 + (k0 - 32);
                float4 f0 = *(const float4*)src;
                float4 f1 = *(const float4*)(src + 4);
                *(short8*)&hb[row * 56 + c * 8] = cvt8(f0, f1);
            }
        }
    }
    wave_lds_fence();   // q, iml, he all visible to this wave

    // ---- P2: qc = [q|1] @ WacF via MFMA (bias row folded at k=48) ----
    {
        short8 afq[2];
        #pragma unroll
        for (int ks = 0; ks < 2; ++ks) {
            union { short8 v; ushort s[8]; } a;
            a.v = short8{0,0,0,0,0,0,0,0};
            if (col == 0) {
                int k0 = ks * 32 + g * 8;
                if (k0 < 48) {
                    float4 x = *(const float4*)&qv[k0];
                    float4 y = *(const float4*)&qv[k0 + 4];
                    a.v = cvt8(x, y);
                } else if (k0 == 48) {
                    a.s[0] = 0x3F80;   // bf16(1.0) -> picks up b1 row
                }
            }
            afq[ks] = a.v;
        }
        f32x4 aq[4];
        #pragma unroll
        for (int nt = 0; nt < 4; ++nt) {
            aq[nt] = f32x4{0,0,0,0};
            #pragma unroll
            for (int ks = 0; ks < 2; ++ks) {
                short8 bq = *(const short8*)&WacF[((nt * 2 + ks) * 64 + l) * 8];
                aq[nt] = __builtin_amdgcn_mfma_f32_16x16x32_bf16(afq[ks], bq, aq[nt], 0, 0, 0);
            }
        }
        if (g == 0) {
            #pragma unroll
            for (int nt = 0; nt < 4; ++nt) qclA[w * 64 + nt * 16 + col] = aq[nt][0];
        }
    }

    // ---- P3: S = [he | he*q] @ Wcat via MFMA (rows >= 50 -> zero frags) ----
    f32x4 acc[4][4];
    #pragma unroll
    for (int m = 0; m < 4; ++m)
        #pragma unroll
        for (int n = 0; n < 4; ++n) acc[m][n] = f32x4{0,0,0,0};

    #pragma unroll
    for (int ks = 0; ks < 3; ++ks) {
        short8 af[4];
        #pragma unroll
        for (int mt = 0; mt < 4; ++mt) {
            int row = mt * 16 + col;
            short8 v = short8{0,0,0,0,0,0,0,0};
            if (row < 50) {
                if (ks == 0)      v = lds8(hb, row, g);
                else if (ks == 1) v = (g < 2) ? lds8(hb, row, 4 + g)
                                              : scale8(hb, qv, row, g - 2, (g - 2) * 8);
                else              v = scale8(hb, qv, row, 2 + g, 16 + g * 8);
            }
            af[mt] = v;
        }
        #pragma unroll
        for (int nt = 0; nt < 4; ++nt) {
            short8 bf = *(const short8*)&WcFrag[((nt * 3 + ks) * 64 + l) * 8];
            #pragma unroll
            for (int mt = 0; mt < 4; ++mt)
                acc[mt][nt] = __builtin_amdgcn_mfma_f32_16x16x32_bf16(af[mt], bf, acc[mt][nt], 0, 0, 0);
        }
    }
    wave_lds_fence();   // qcl ready

    // ---- P4: score = relu(S + qc) . w23 + c23, mask ----
    {
        float qcv[4], wv[4];
        #pragma unroll
        for (int nt = 0; nt < 4; ++nt) {
            qcv[nt] = qclA[w * 64 + nt * 16 + col];
            wv[nt]  = w23g[nt * 16 + col];
        }
        float c23 = c23g[0];
        #pragma unroll
        for (int mt = 0; mt < 4; ++mt) {
            #pragma unroll
            for (int i = 0; i < 4; ++i) {
                float s = fmaxf(acc[mt][0][i] + qcv[0], 0.f) * wv[0]
                        + fmaxf(acc[mt][1][i] + qcv[1], 0.f) * wv[1]
                        + fmaxf(acc[mt][2][i] + qcv[2], 0.f) * wv[2]
                        + fmaxf(acc[mt][3][i] + qcv[3], 0.f) * wv[3];
                s += __shfl_xor(s, 1, 16);
                s += __shfl_xor(s, 2, 16);
                s += __shfl_xor(s, 4, 16);
                s += __shfl_xor(s, 8, 16);
                int row = mt * 16 + g * 4 + i;
                if (col == 0 && row < NL)
                    sclA[w * 52 + row] = (imlA[w * 52 + row] == 0) ? 0.f : (s + c23);
            }
        }
    }
    wave_lds_fence();   // scl ready

    // ---- P5: pooled -> feat global ----
    if (l < 48) {
        float p = 0.f;
        #pragma unroll
        for (int r4 = 0; r4 < 48; r4 += 4) {
            float4 sv = *(const float4*)&sclA[w * 52 + r4];
            p = fmaf(sv.x, bf2f(hb[(r4 + 0) * 56 + l]), p);
            p = fmaf(sv.y, bf2f(hb[(r4 + 1) * 56 + l]), p);
            p = fmaf(sv.z, bf2f(hb[(r4 + 2) * 56 + l]), p);
            p = fmaf(sv.w, bf2f(hb[(r4 + 3) * 56 + l]), p);
        }
        float2 st = *(const float2*)&sclA[w * 52 + 48];
        p = fmaf(st.x, bf2f(hb[48 * 56 + l]), p);
        p = fmaf(st.y, bf2f(hb[49 * 56 + l]), p);
        feat[fb + 48 + l] = f2bf(p);
    }
}

// ================= k2: MLP 128->200->80->1, pure MFMA, 1 wave = 16 rows =================
__global__ __launch_bounds__(64, 4) void k2_fc(
    const ushort* __restrict__ feat,
    const ushort* __restrict__ W1frag,
    const ushort* __restrict__ W2frag,
    const float* __restrict__ fb1, const float* __restrict__ fb2,
    const float* __restrict__ fw3, const float* __restrict__ fb3,
    const int* __restrict__ items,
    float* __restrict__ logits)
{
    __shared__ __align__(16) ushort x1s[16 * 256];  // [16 rows][224+pad] swizzled bf16

    const int l = threadIdx.x;
    const int r0 = blockIdx.x * 16;
    const int col = l & 15, g = l >> 4;

    // ---- layer 1: 13nt x 4ks MFMA, A from feat global ----
    short8 afr[4];
    #pragma unroll
    for (int ks = 0; ks < 4; ++ks)
        afr[ks] = *(const short8*)&feat[(size_t)(r0 + col) * 128 + ks * 32 + g * 8];

    f32x4 acc[13];
    #pragma unroll
    for (int nt = 0; nt < 13; ++nt) acc[nt] = f32x4{0,0,0,0};
    #pragma unroll
    for (int nt = 0; nt < 13; ++nt)
        #pragma unroll
        for (int ks = 0; ks < 4; ++ks) {
            short8 bf = *(const short8*)&W1frag[((nt * 4 + ks) * 64 + l) * 8];
            acc[nt] = __builtin_amdgcn_mfma_f32_16x16x32_bf16(afr[ks], bf, acc[nt], 0, 0, 0);
        }

    // zero pad chunks 26,27 (k 208..223) of x1
    if (l < 32) {
        int row = l >> 1, c = 26 + (l & 1);
        *(short8*)&x1s[row * 256 + ((c ^ (row & 7)) << 3)] = short8{0,0,0,0,0,0,0,0};
    }
    // relu + bias -> x1 LDS (bf16, XOR-swizzled chunks)
    #pragma unroll
    for (int nt = 0; nt < 13; ++nt) {
        int n = nt * 16 + col;
        float bias = (n < 200) ? fb1[n] : 0.f;
        #pragma unroll
        for (int i = 0; i < 4; ++i) {
            int row = g * 4 + i;
            float v = fmaxf(acc[nt][i] + bias, 0.f);
            int sw = (n >> 3) ^ (row & 7);
            x1s[row * 256 + sw * 8 + (n & 7)] = f2bf(v);
        }
    }
    wave_lds_fence();

    // ---- layer 2: 6nt x 7ks MFMA, A from x1s ----
    f32x4 acc2[6];
    #pragma unroll
    for (int nt = 0; nt < 6; ++nt) acc2[nt] = f32x4{0,0,0,0};
    #pragma unroll
    for (int ks = 0; ks < 7; ++ks) {
        int chunk = ks * 4 + g;
        short8 a = *(const short8*)&x1s[col * 256 + ((chunk ^ (col & 7)) << 3)];
        #pragma unroll
        for (int nt = 0; nt < 6; ++nt) {
            short8 bf = *(const short8*)&W2frag[((nt * 7 + ks) * 64 + l) * 8];
            acc2[nt] = __builtin_amdgcn_mfma_f32_16x16x32_bf16(a, bf, acc2[nt], 0, 0, 0);
        }
    }

    // ---- layer 3: dot over 80 + sigmoid + mask ----
    {
        float s[4] = {0.f, 0.f, 0.f, 0.f};
        #pragma unroll
        for (int nt = 0; nt < 5; ++nt) {
            int n = nt * 16 + col;
            float b2v = fb2[n], w3v = fw3[n];
            #pragma unroll
            for (int i = 0; i < 4; ++i)
                s[i] = fmaf(fmaxf(acc2[nt][i] + b2v, 0.f), w3v, s[i]);
        }
        #pragma unroll
        for (int i = 0; i < 4; ++i) {
            s[i] += __shfl_xor(s[i], 1, 16);
            s[i] += __shfl_xor(s[i], 2, 16);
            s[i] += __shfl_xor(s[i], 4, 16);
            s[i] += __shfl_xor(s[i], 8, 16);
        }
        if (col == 0) {
            float b3 = fb3[0];
            #pragma unroll
            for (int i = 0; i < 4; ++i) {
                int row = r0 + g * 4 + i;
                float lg = (items[row] == 0) ? -INFINITY
                                             : 1.f / (1.f + __expf(-(s[i] + b3)));
                logits[row] = lg;
            }
        }
    }
}

// ================= k3: masked softmax =================
__global__ __launch_bounds__(256) void k3_softmax(
    const float* __restrict__ logits, float* __restrict__ out)
{
    const int b = blockIdx.x, t = threadIdx.x;
    __shared__ float red[4];
    float v = logits[b * 256 + t];
    float m = v;
    #pragma unroll
    for (int off = 32; off; off >>= 1) m = fmaxf(m, __shfl_xor(m, off, 64));
    if ((t & 63) == 0) red[t >> 6] = m;
    __syncthreads();
    float mx = fmaxf(fmaxf(red[0], red[1]), fmaxf(red[2], red[3]));
    float e = __expf(v - mx);
    float s = e;
    #pragma unroll
    for (int off = 32; off; off >>= 1) s += __shfl_xor(s, off, 64);
    __syncthreads();
    if ((t & 63) == 0) red[t >> 6] = s;
    __syncthreads();
    float tot = red[0] + red[1] + red[2] + red[3];
    out[b * 256 + t] = e / tot;
}

extern "C" void kernel_launch(void* const* d_in, const int* in_sizes, int n_in,
                              void* d_out, int out_size, void* d_ws, size_t ws_size,
                              hipStream_t stream)
{
    const float* emb_user = (const float*)d_in[0];
    const float* emb_item = (const float*)d_in[1];
    const float* emb_cate = (const float*)d_in[2];
    const float* aw1 = (const float*)d_in[3];
    const float* ab1 = (const float*)d_in[4];
    const float* aw2 = (const float*)d_in[5];
    const float* ab2 = (const float*)d_in[6];
    const float* aw3 = (const float*)d_in[7];
    const float* ab3 = (const float*)d_in[8];
    const float* fw1 = (const float*)d_in[9];
    const float* fb1 = (const float*)d_in[10];
    const float* fw2 = (const float*)d_in[11];
    const float* fb2 = (const float*)d_in[12];
    const float* fw3 = (const float*)d_in[13];
    const float* fb3 = (const float*)d_in[14];
    const int* user  = (const int*)d_in[15];
    const int* items = (const int*)d_in[16];
    const int* cates = (const int*)d_in[17];
    const int* ii    = (const int*)d_in[18];
    const int* ic    = (const int*)d_in[19];

    char* ws = (char*)d_ws;
    ushort* feat   = (ushort*)(ws + WS_FEAT);
    float*  logits = (float*) (ws + WS_LOGITS);
    ushort* W1frag = (ushort*)(ws + WS_W1FRAG);
    ushort* W2frag = (ushort*)(ws + WS_W2FRAG);
    ushort* WcFrag = (ushort*)(ws + WS_WCFRAG);
    ushort* WacF   = (ushort*)(ws + WS_WACF);
    float*  w23    = (float*) (ws + WS_W23);
    float*  c23    = (float*) (ws + WS_C23);

    k0_prep<<<229, 256, 0, stream>>>(aw1, ab1, ab2, aw2, aw3, ab3, fw1, fw2,
                                     W1frag, W2frag, WcFrag, WacF, w23, c23);
    kA_attn<<<BN_TOT / 4, 256, 0, stream>>>(emb_user, emb_item, emb_cate,
                                            user, items, cates, ii, ic,
                                            WcFrag, WacF, w23, c23, feat);
    k2_fc<<<BN_TOT / 16, 64, 0, stream>>>(feat, W1frag, W2frag,
                                          fb1, fb2, fw3, fb3, items, logits);
    k3_softmax<<<32, 256, 0, stream>>>(logits, (float*)d_out);
}

// Round 9
// 140.293 us; speedup vs baseline: 1.2745x; 1.2745x over previous
//
#include <hip/hip_runtime.h>
#include <hip/hip_bf16.h>
#include <math.h>

// DIN forward, MI355X gfx950. B=32,N=256,L=50, D=48; feat 128 -> 200 -> 80 -> 1.
// Algebra: ai@W1 = qc + [he | he*q] @ Wcat   (Wcat constant across bn)
//   qc = q@(W1a+W1c) + b1, computed via MFMA with a folded bias row (k=48 -> 1*b1)
//   layers 2+3 of LAU collapse: score = relu(h1) . (W2@w3) + (b2@w3+b3)
// k0: pre-lay ALL weights as bf16 MFMA B-fragments in ws.
// kA: per-bn attention, fully wave-private (NO __syncthreads).
// k2: MLP via MFMA, 1 wave = 16 rows, wave-private LDS (NO __syncthreads).
// k3: masked softmax over N=256.
// ROUND 9 = exact revert to round-4 source (best measured: 142.1 us).

typedef short short8 __attribute__((ext_vector_type(8)));
typedef float f32x4 __attribute__((ext_vector_type(4)));

#define NL 50
#define BN_TOT 8192

__device__ __forceinline__ ushort f2bf(float x) {
    union { __hip_bfloat16 b; ushort u; } c;
    c.b = __float2bfloat16(x);          // RNE; compiler packs pairs into v_cvt_pk_bf16_f32
    return c.u;
}
__device__ __forceinline__ float bf2f(ushort h) {
    union { uint u; float f; } v; v.u = ((uint)h) << 16;
    return v.f;
}
// same-wave LDS RAW boundary: DS ops complete in order per wave; fence compiler + counters
__device__ __forceinline__ void wave_lds_fence() {
    asm volatile("s_waitcnt lgkmcnt(0)" ::: "memory");
}

// ---- ws layout (bytes) ----
#define WS_FEAT   0                       // bf16 8192*128  = 2097152
#define WS_LOGITS 2097152                 // f32  8192
#define WS_W1FRAG 2129920                 // bf16 52*512
#define WS_W2FRAG 2183168                 // bf16 42*512
#define WS_WCFRAG 2226176                 // bf16 12*512
#define WS_WACF   2238464                 // bf16 8*512
#define WS_W23    2250752                 // f32  64
#define WS_C23    2251008                 // f32  1

// ================= k0_prep: weight fragments =================
__global__ __launch_bounds__(256) void k0_prep(
    const float* __restrict__ aw1, const float* __restrict__ ab1,
    const float* __restrict__ ab2,
    const float* __restrict__ aw2, const float* __restrict__ aw3,
    const float* __restrict__ ab3,
    const float* __restrict__ fw1, const float* __restrict__ fw2,
    ushort* __restrict__ W1frag, ushort* __restrict__ W2frag,
    ushort* __restrict__ WcFrag, ushort* __restrict__ WacF,
    float* __restrict__ w23, float* __restrict__ c23)
{
    const int b = blockIdx.x, t = threadIdx.x;
    if (b < 104) {                       // W1frag: fw1[128][200] -> 13nt x 4ks
        int e = b * 256 + t;
        if (e < 26624) {
            int f = e >> 9, r = e & 511, l = r >> 3, j = r & 7;
            int nt = f >> 2, ks = f & 3;
            int k = ks * 32 + (l >> 4) * 8 + j, n = nt * 16 + (l & 15);
            float v = (n < 200) ? fw1[k * 200 + n] : 0.f;
            W1frag[e] = f2bf(v);
        }
    } else if (b < 188) {                // W2frag: fw2[200][80] -> 6nt x 7ks (pad K224,N96)
        int e = (b - 104) * 256 + t;
        if (e < 21504) {
            int f = e >> 9, r = e & 511, l = r >> 3, j = r & 7;
            int nt = f / 7, ks = f % 7;
            int k = ks * 32 + (l >> 4) * 8 + j, n = nt * 16 + (l & 15);
            float v = (k < 200 && n < 80) ? fw2[k * 80 + n] : 0.f;
            W2frag[e] = f2bf(v);
        }
    } else if (b < 212) {                // WcFrag: Wcat[96][64] -> 4nt x 3ks
        int e = (b - 188) * 256 + t;     // 6144 elems
        int f = e >> 9, r = e & 511, l = r >> 3, j = r & 7;
        int nt = f / 3, ks = f % 3;
        int k = ks * 32 + (l >> 4) * 8 + j, n = nt * 16 + (l & 15);
        float v = (k < 48) ? (aw1[(48 + k) * 64 + n] - aw1[(96 + k) * 64 + n])
                           : aw1[(144 + (k - 48)) * 64 + n];
        WcFrag[e] = f2bf(v);
    } else if (b < 228) {                // WacF: (W1a+W1c)[48][64] + bias row k=48
        int e = (b - 212) * 256 + t;     // 4096 elems
        int f = e >> 9, r = e & 511, l = r >> 3, j = r & 7;
        int nt = f >> 1, ks = f & 1;
        int k = ks * 32 + (l >> 4) * 8 + j, n = nt * 16 + (l & 15);
        float v = (k < 48) ? (aw1[k * 64 + n] + aw1[(96 + k) * 64 + n])
                           : ((k == 48) ? ab1[n] : 0.f);
        WacF[e] = f2bf(v);
    } else {                             // w23, c23
        if (t < 64) {
            float s = 0.f;
            #pragma unroll
            for (int jj = 0; jj < 16; ++jj) s = fmaf(aw2[t * 16 + jj], aw3[jj], s);
            w23[t] = s;
        }
        if (t == 64) {
            float c = ab3[0];
            #pragma unroll
            for (int jj = 0; jj < 16; ++jj) c = fmaf(ab2[jj], aw3[jj], c);
            c23[0] = c;
        }
    }
}

// ================= kA: attention (1 wave = 1 bn, no barriers) =================
__device__ __forceinline__ short8 lds8(const ushort* hb, int row, int c) {
    return *(const short8*)&hb[row * 56 + c * 8];
}
__device__ __forceinline__ short8 scale8(const ushort* hb, const float* qv,
                                         int row, int c, int qb) {
    short8 a = lds8(hb, row, c);
    union { short8 v; ushort s[8]; } o;
    const ushort* as = (const ushort*)&a;
    #pragma unroll
    for (int j = 0; j < 8; ++j) o.s[j] = f2bf(bf2f(as[j]) * qv[qb + j]);
    return o.v;
}

__global__ __launch_bounds__(256, 4) void kA_attn(
    const float* __restrict__ emb_user,
    const float* __restrict__ emb_item,
    const float* __restrict__ emb_cate,
    const int* __restrict__ user,
    const int* __restrict__ items,
    const int* __restrict__ cates,
    const int* __restrict__ ii,
    const int* __restrict__ ic,
    const ushort* __restrict__ WcFrag,
    const ushort* __restrict__ WacF,
    const float* __restrict__ w23g,
    const float* __restrict__ c23g,
    ushort* __restrict__ feat)
{
    __shared__ __align__(16) ushort heb[4][64 * 56];   // he bf16 [64 rows][48+8pad]
    __shared__ __align__(16) float  qf[4][48];
    __shared__ __align__(16) float  uf[4][32];
    __shared__ float  qcl[4][64];
    __shared__ float  scl[4][52];
    __shared__ int    iml[4][52];
    __shared__ int    icl[4][52];

    const int t = threadIdx.x;
    const int w = t >> 6, l = t & 63;
    const int bn = blockIdx.x * 4 + w;
    const int col = l & 15, g = l >> 4;

    ushort* hb = &heb[w][0];
    const float* qv = &qf[w][0];

    // ---- P0: q, u, index gathers (all wave-private) ----
    if (l < 12) {
        int it_ = items[bn], ct = cates[bn];
        float4 v = (l < 8) ? ((const float4*)emb_item)[(size_t)it_ * 8 + l]
                           : ((const float4*)emb_cate)[(size_t)ct * 4 + (l - 8)];
        *(float4*)&qf[w][l * 4] = v;
    } else if (l >= 16 && l < 24) {
        int ur = user[bn];
        *(float4*)&uf[w][(l - 16) * 4] = ((const float4*)emb_user)[(size_t)ur * 8 + (l - 16)];
    }
    if (l < NL) {
        iml[w][l] = ii[(size_t)bn * NL + l];
        icl[w][l] = ic[(size_t)bn * NL + l];
    }
    wave_lds_fence();

    // ---- P1: he gather -> LDS bf16 (rows >= 50 left garbage: D-rows are independent) ----
    #pragma unroll
    for (int e0 = 0; e0 < 300; e0 += 64) {
        int e = e0 + l;
        if (e < 300) {
            int row = e / 6, c = e - row * 6;
            int k0 = c * 8;
            const float* src = (k0 < 32)
                ? emb_item + (size_t)iml[w][row] * 32 + k0
                : emb_cate + (size_t)icl[w][row] * 16 + (k0 - 32);
            float4 f0 = *(const float4*)src;
            float4 f1 = *(const float4*)(src + 4);
            union { short8 v; ushort s[8]; } o;
            o.s[0] = f2bf(f0.x); o.s[1] = f2bf(f0.y); o.s[2] = f2bf(f0.z); o.s[3] = f2bf(f0.w);
            o.s[4] = f2bf(f1.x); o.s[5] = f2bf(f1.y); o.s[6] = f2bf(f1.z); o.s[7] = f2bf(f1.w);
            *(short8*)&hb[row * 56 + c * 8] = o.v;
        }
    }
    wave_lds_fence();

    // ---- P2: qc = [q|1] @ WacF via MFMA (bias row folded at k=48) ----
    {
        short8 afq[2];
        #pragma unroll
        for (int ks = 0; ks < 2; ++ks) {
            union { short8 v; ushort s[8]; } a;
            a.v = short8{0,0,0,0,0,0,0,0};
            if (col == 0) {
                int k0 = ks * 32 + g * 8;
                if (k0 < 48) {
                    float4 x = *(const float4*)&qf[w][k0];
                    float4 y = *(const float4*)&qf[w][k0 + 4];
                    a.s[0] = f2bf(x.x); a.s[1] = f2bf(x.y); a.s[2] = f2bf(x.z); a.s[3] = f2bf(x.w);
                    a.s[4] = f2bf(y.x); a.s[5] = f2bf(y.y); a.s[6] = f2bf(y.z); a.s[7] = f2bf(y.w);
                } else if (k0 == 48) {
                    a.s[0] = 0x3F80;   // bf16(1.0) -> picks up b1 row
                }
            }
            afq[ks] = a.v;
        }
        f32x4 aq[4];
        #pragma unroll
        for (int nt = 0; nt < 4; ++nt) {
            aq[nt] = f32x4{0,0,0,0};
            #pragma unroll
            for (int ks = 0; ks < 2; ++ks) {
                short8 bq = *(const short8*)&WacF[((nt * 2 + ks) * 64 + l) * 8];
                aq[nt] = __builtin_amdgcn_mfma_f32_16x16x32_bf16(afq[ks], bq, aq[nt], 0, 0, 0);
            }
        }
        if (g == 0) {
            #pragma unroll
            for (int nt = 0; nt < 4; ++nt) qcl[w][nt * 16 + col] = aq[nt][0];
        }
    }

    // ---- P3: S = [he | he*q] @ Wcat via MFMA ----
    f32x4 acc[4][4];
    #pragma unroll
    for (int m = 0; m < 4; ++m)
        #pragma unroll
        for (int n = 0; n < 4; ++n) acc[m][n] = f32x4{0,0,0,0};

    #pragma unroll
    for (int ks = 0; ks < 3; ++ks) {
        short8 af[4];
        #pragma unroll
        for (int mt = 0; mt < 4; ++mt) {
            int row = mt * 16 + col;
            if (ks == 0)       af[mt] = lds8(hb, row, g);
            else if (ks == 1)  af[mt] = (g < 2) ? lds8(hb, row, 4 + g)
                                                : scale8(hb, qv, row, g - 2, (g - 2) * 8);
            else               af[mt] = scale8(hb, qv, row, 2 + g, 16 + g * 8);
        }
        #pragma unroll
        for (int nt = 0; nt < 4; ++nt) {
            short8 bf = *(const short8*)&WcFrag[((nt * 3 + ks) * 64 + l) * 8];
            #pragma unroll
            for (int mt = 0; mt < 4; ++mt)
                acc[mt][nt] = __builtin_amdgcn_mfma_f32_16x16x32_bf16(af[mt], bf, acc[mt][nt], 0, 0, 0);
        }
    }
    wave_lds_fence();   // qcl written (P2) before P4 reads

    // ---- P4: score = relu(S + qc) . w23 + c23, mask ----
    {
        float qcv[4], wv[4];
        #pragma unroll
        for (int nt = 0; nt < 4; ++nt) {
            qcv[nt] = qcl[w][nt * 16 + col];
            wv[nt]  = w23g[nt * 16 + col];
        }
        float c23 = c23g[0];
        #pragma unroll
        for (int mt = 0; mt < 4; ++mt) {
            #pragma unroll
            for (int i = 0; i < 4; ++i) {
                float s = fmaxf(acc[mt][0][i] + qcv[0], 0.f) * wv[0]
                        + fmaxf(acc[mt][1][i] + qcv[1], 0.f) * wv[1]
                        + fmaxf(acc[mt][2][i] + qcv[2], 0.f) * wv[2]
                        + fmaxf(acc[mt][3][i] + qcv[3], 0.f) * wv[3];
                s += __shfl_xor(s, 1, 16);
                s += __shfl_xor(s, 2, 16);
                s += __shfl_xor(s, 4, 16);
                s += __shfl_xor(s, 8, 16);
                int row = mt * 16 + g * 4 + i;
                if (col == 0 && row < NL)
                    scl[w][row] = (iml[w][row] == 0) ? 0.f : (s + c23);
            }
        }
    }
    wave_lds_fence();   // scl written before P5 reads

    // ---- P5: pooled + feat writes ----
    const size_t fb = (size_t)bn * 128;
    if (l < 48) {
        float p = 0.f;
        #pragma unroll
        for (int r4 = 0; r4 < 48; r4 += 4) {
            float4 sv = *(const float4*)&scl[w][r4];
            p = fmaf(sv.x, bf2f(hb[(r4 + 0) * 56 + l]), p);
            p = fmaf(sv.y, bf2f(hb[(r4 + 1) * 56 + l]), p);
            p = fmaf(sv.z, bf2f(hb[(r4 + 2) * 56 + l]), p);
            p = fmaf(sv.w, bf2f(hb[(r4 + 3) * 56 + l]), p);
        }
        float2 st = *(const float2*)&scl[w][48];
        p = fmaf(st.x, bf2f(hb[48 * 56 + l]), p);
        p = fmaf(st.y, bf2f(hb[49 * 56 + l]), p);
        feat[fb + 48 + l] = f2bf(p);
        feat[fb + l] = f2bf(qv[l]);
    }
    if (l < 32) feat[fb + 96 + l] = f2bf(uf[w][l]);
}

// ================= k2: MLP 128->200->80->1, pure MFMA, 1 wave = 16 rows =================
__global__ __launch_bounds__(64, 4) void k2_fc(
    const ushort* __restrict__ feat,
    const ushort* __restrict__ W1frag,
    const ushort* __restrict__ W2frag,
    const float* __restrict__ fb1, const float* __restrict__ fb2,
    const float* __restrict__ fw3, const float* __restrict__ fb3,
    const int* __restrict__ items,
    float* __restrict__ logits)
{
    __shared__ __align__(16) ushort x1s[16 * 256];  // [16 rows][224+pad] swizzled bf16

    const int l = threadIdx.x;
    const int r0 = blockIdx.x * 16;
    const int col = l & 15, g = l >> 4;

    // ---- layer 1: 13nt x 4ks MFMA, A from feat global ----
    short8 afr[4];
    #pragma unroll
    for (int ks = 0; ks < 4; ++ks)
        afr[ks] = *(const short8*)&feat[(size_t)(r0 + col) * 128 + ks * 32 + g * 8];

    f32x4 acc[13];
    #pragma unroll
    for (int nt = 0; nt < 13; ++nt) acc[nt] = f32x4{0,0,0,0};
    #pragma unroll
    for (int nt = 0; nt < 13; ++nt)
        #pragma unroll
        for (int ks = 0; ks < 4; ++ks) {
            short8 bf = *(const short8*)&W1frag[((nt * 4 + ks) * 64 + l) * 8];
            acc[nt] = __builtin_amdgcn_mfma_f32_16x16x32_bf16(afr[ks], bf, acc[nt], 0, 0, 0);
        }

    // zero pad chunks 26,27 (k 208..223) of x1
    if (l < 32) {
        int row = l >> 1, c = 26 + (l & 1);
        *(short8*)&x1s[row * 256 + ((c ^ (row & 7)) << 3)] = short8{0,0,0,0,0,0,0,0};
    }
    // relu + bias -> x1 LDS (bf16, XOR-swizzled chunks)
    #pragma unroll
    for (int nt = 0; nt < 13; ++nt) {
        int n = nt * 16 + col;
        float bias = (n < 200) ? fb1[n] : 0.f;
        #pragma unroll
        for (int i = 0; i < 4; ++i) {
            int row = g * 4 + i;
            float v = fmaxf(acc[nt][i] + bias, 0.f);
            int sw = (n >> 3) ^ (row & 7);
            x1s[row * 256 + sw * 8 + (n & 7)] = f2bf(v);
        }
    }
    wave_lds_fence();

    // ---- layer 2: 6nt x 7ks MFMA, A from x1s ----
    f32x4 acc2[6];
    #pragma unroll
    for (int nt = 0; nt < 6; ++nt) acc2[nt] = f32x4{0,0,0,0};
    #pragma unroll
    for (int ks = 0; ks < 7; ++ks) {
        int chunk = ks * 4 + g;
        short8 a = *(const short8*)&x1s[col * 256 + ((chunk ^ (col & 7)) << 3)];
        #pragma unroll
        for (int nt = 0; nt < 6; ++nt) {
            short8 bf = *(const short8*)&W2frag[((nt * 7 + ks) * 64 + l) * 8];
            acc2[nt] = __builtin_amdgcn_mfma_f32_16x16x32_bf16(a, bf, acc2[nt], 0, 0, 0);
        }
    }

    // ---- layer 3: dot over 80 + sigmoid + mask ----
    {
        float s[4] = {0.f, 0.f, 0.f, 0.f};
        #pragma unroll
        for (int nt = 0; nt < 5; ++nt) {
            int n = nt * 16 + col;
            float b2v = fb2[n], w3v = fw3[n];
            #pragma unroll
            for (int i = 0; i < 4; ++i)
                s[i] = fmaf(fmaxf(acc2[nt][i] + b2v, 0.f), w3v, s[i]);
        }
        #pragma unroll
        for (int i = 0; i < 4; ++i) {
            s[i] += __shfl_xor(s[i], 1, 16);
            s[i] += __shfl_xor(s[i], 2, 16);
            s[i] += __shfl_xor(s[i], 4, 16);
            s[i] += __shfl_xor(s[i], 8, 16);
        }
        if (col == 0) {
            float b3 = fb3[0];
            #pragma unroll
            for (int i = 0; i < 4; ++i) {
                int row = r0 + g * 4 + i;
                float lg = (items[row] == 0) ? -INFINITY
                                             : 1.f / (1.f + __expf(-(s[i] + b3)));
                logits[row] = lg;
            }
        }
    }
}

// ================= k3: masked softmax =================
__global__ __launch_bounds__(256) void k3_softmax(
    const float* __restrict__ logits, float* __restrict__ out)
{
    const int b = blockIdx.x, t = threadIdx.x;
    __shared__ float red[4];
    float v = logits[b * 256 + t];
    float m = v;
    #pragma unroll
    for (int off = 32; off; off >>= 1) m = fmaxf(m, __shfl_xor(m, off, 64));
    if ((t & 63) == 0) red[t >> 6] = m;
    __syncthreads();
    float mx = fmaxf(fmaxf(red[0], red[1]), fmaxf(red[2], red[3]));
    float e = __expf(v - mx);
    float s = e;
    #pragma unroll
    for (int off = 32; off; off >>= 1) s += __shfl_xor(s, off, 64);
    __syncthreads();
    if ((t & 63) == 0) red[t >> 6] = s;
    __syncthreads();
    float tot = red[0] + red[1] + red[2] + red[3];
    out[b * 256 + t] = e / tot;
}

extern "C" void kernel_launch(void* const* d_in, const int* in_sizes, int n_in,
                              void* d_out, int out_size, void* d_ws, size_t ws_size,
                              hipStream_t stream)
{
    const float* emb_user = (const float*)d_in[0];
    const float* emb_item = (const float*)d_in[1];
    const float* emb_cate = (const float*)d_in[2];
    const float* aw1 = (const float*)d_in[3];
    const float* ab1 = (const float*)d_in[4];
    const float* aw2 = (const float*)d_in[5];
    const float* ab2 = (const float*)d_in[6];
    const float* aw3 = (const float*)d_in[7];
    const float* ab3 = (const float*)d_in[8];
    const float* fw1 = (const float*)d_in[9];
    const float* fb1 = (const float*)d_in[10];
    const float* fw2 = (const float*)d_in[11];
    const float* fb2 = (const float*)d_in[12];
    const float* fw3 = (const float*)d_in[13];
    const float* fb3 = (const float*)d_in[14];
    const int* user  = (const int*)d_in[15];
    const int* items = (const int*)d_in[16];
    const int* cates = (const int*)d_in[17];
    const int* ii    = (const int*)d_in[18];
    const int* ic    = (const int*)d_in[19];

    char* ws = (char*)d_ws;
    ushort* feat   = (ushort*)(ws + WS_FEAT);
    float*  logits = (float*) (ws + WS_LOGITS);
    ushort* W1frag = (ushort*)(ws + WS_W1FRAG);
    ushort* W2frag = (ushort*)(ws + WS_W2FRAG);
    ushort* WcFrag = (ushort*)(ws + WS_WCFRAG);
    ushort* WacF   = (ushort*)(ws + WS_WACF);
    float*  w23    = (float*) (ws + WS_W23);
    float*  c23    = (float*) (ws + WS_C23);

    k0_prep<<<229, 256, 0, stream>>>(aw1, ab1, ab2, aw2, aw3, ab3, fw1, fw2,
                                     W1frag, W2frag, WcFrag, WacF, w23, c23);
    kA_attn<<<BN_TOT / 4, 256, 0, stream>>>(emb_user, emb_item, emb_cate,
                                            user, items, cates, ii, ic,
                                            WcFrag, WacF, w23, c23, feat);
    k2_fc<<<BN_TOT / 16, 64, 0, stream>>>(feat, W1frag, W2frag,
                                          fb1, fb2, fw3, fb3, items, logits);
    k3_softmax<<<32, 256, 0, stream>>>(logits, (float*)d_out);
}